// Round 5
// baseline (5222.781 us; speedup 1.0000x reference)
//
#include <hip/hip_runtime.h>

#define NFULL 33024
#define FPS_T 1024   // threads per FPS block (16 waves, 4/SIMD, 128-VGPR budget)
#define FPS_J 33     // points per thread: 33*1024 = 33792 >= 33024

// ---- x1[b,o,k] = sum_i f[b,i] * ps_w[i,o,k] + ps_b[o] ; col = o*256+k ----
__global__ void k_ps(const float* __restrict__ feat,
                     const float* __restrict__ psw,
                     const float* __restrict__ psb,
                     float* __restrict__ out)
{
    __shared__ float fs[16384];   // all of f (32x512), 64 KB
    const int tid = threadIdx.x;
    for (int k = tid; k < 16384; k += 256) fs[k] = feat[k];
    __syncthreads();
    const int col = blockIdx.x * 256 + tid;    // 0..32767
    float acc[32];
    #pragma unroll
    for (int b = 0; b < 32; ++b) acc[b] = 0.f;
    for (int i = 0; i < 512; i += 4) {
        const float w0 = psw[(i+0)*32768 + col];
        const float w1 = psw[(i+1)*32768 + col];
        const float w2 = psw[(i+2)*32768 + col];
        const float w3 = psw[(i+3)*32768 + col];
        #pragma unroll
        for (int b = 0; b < 32; ++b) {
            const float4 f4 = *(const float4*)&fs[b*512 + i];
            acc[b] += f4.x*w0 + f4.y*w1 + f4.z*w2 + f4.w*w3;
        }
    }
    const float bias = psb[col >> 8];
    #pragma unroll
    for (int b = 0; b < 32; ++b) out[b*32768 + col] = acc[b] + bias;
}

// ---- fb[wsel][b,o] = sum_{i<512} f[b,i] * w[o*640 + 128 + i]  (fr-fold) ----
__global__ void k_fb(const float* __restrict__ feat,
                     const float* __restrict__ wa, const float* __restrict__ wb,
                     const float* __restrict__ wc, const float* __restrict__ wd,
                     float* __restrict__ fb)
{
    const int tid = blockIdx.x * 256 + threadIdx.x;  // 0..16383
    const int wsel = tid >> 12;
    const int r = tid & 4095;
    const int b = r >> 7, o = r & 127;
    const float* w = (wsel == 0 ? wa : wsel == 1 ? wb : wsel == 2 ? wc : wd) + o*640 + 128;
    const float* f = feat + b*512;
    float acc = 0.f;
    for (int i = 0; i < 512; i += 4) {
        const float4 wv = *(const float4*)(w + i);
        const float4 fv = *(const float4*)(f + i);
        acc += wv.x*fv.x + wv.y*fv.y + wv.z*fv.z + wv.w*fv.w;
    }
    fb[tid] = acc;
}

// ---- out[b,o,n] = relu?( sum_i w[o,i]*x[b,i,n] + bias[o] + fb[b,o] + add[b,o,n] )
__global__ void k_conv(const float* __restrict__ x,
                       const float* __restrict__ w,
                       const float* __restrict__ bias,
                       const float* __restrict__ fb,
                       const float* __restrict__ add,
                       float* __restrict__ out,
                       const int O, const int K, const int ldw, const int relu)
{
    const int bo = blockIdx.x;
    const int b = bo / O;
    const int o = bo - b * O;
    const int n = threadIdx.x;
    const float* __restrict__ wr = w + o * ldw;
    const float* __restrict__ xb = x + (b * K) * 256 + n;
    float acc = 0.f;
    for (int i = 0; i < K; i += 4) {
        const float4 wv = *(const float4*)(wr + i);
        acc += wv.x * xb[(i+0) << 8];
        acc += wv.y * xb[(i+1) << 8];
        acc += wv.z * xb[(i+2) << 8];
        acc += wv.w * xb[(i+3) << 8];
    }
    acc += bias[o];
    if (fb)   acc += fb[b * O + o];
    if (add)  acc += add[bo * 256 + n];
    if (relu) acc = fmaxf(acc, 0.f);
    out[bo * 256 + n] = acc;
}

// ---- pcd transpose -> d_out and points[0:256) ; also mirrors into P ----
__global__ void k_pcd(const float* __restrict__ comp,
                      float* __restrict__ pcd_out,
                      float* __restrict__ P)
{
    const int tid = blockIdx.x * 256 + threadIdx.x;  // 0..8191
    const int b = tid >> 8, n = tid & 255;
    const float cx = comp[(b*3+0)*256 + n];
    const float cy = comp[(b*3+1)*256 + n];
    const float cz = comp[(b*3+2)*256 + n];
    pcd_out[tid*3+0] = cx; pcd_out[tid*3+1] = cy; pcd_out[tid*3+2] = cz;
    const int pb = b*99072 + n*3;
    P[pb+0] = cx; P[pb+1] = cy; P[pb+2] = cz;
}

// ---- copy partial into P[256:33024) per batch (bitwise) ----
__global__ void k_copy(const float* __restrict__ partial, float* __restrict__ P)
{
    for (int idx = blockIdx.x*256 + threadIdx.x; idx < 32*32768*3; idx += gridDim.x*256) {
        const int b = idx / 98304;          // 32768*3
        const int r = idx - b*98304;
        P[b*99072 + 768 + r] = partial[idx];
    }
}

// ================= farthest point sampling =================
// One 1024-thread block per batch (16 waves = 4/SIMD). The allocator budgets
// 128 VGPRs for this shape (observed fixed across 3 rounds at T=512, where
// 195 floats of state spilled). At J=33 the per-thread state is 99 named
// scalars + ~20 temps < 128 -> register-resident, no spill traffic.
// z stays in LDS (135KB); x,y,d in registers.

#define REP32(M) \
  M(0) M(1) M(2) M(3) M(4) M(5) M(6) M(7) M(8) M(9) \
  M(10) M(11) M(12) M(13) M(14) M(15) M(16) M(17) M(18) M(19) \
  M(20) M(21) M(22) M(23) M(24) M(25) M(26) M(27) M(28) M(29) \
  M(30) M(31)

#define FPS_DECL(i) float px##i, py##i, d##i;

#define FPS_INIT(i) { \
    const int p = (i)*FPS_T + t; \
    px##i = Pb[p*3+0]; py##i = Pb[p*3+1]; zs[p] = Pb[p*3+2]; d##i = 1.0e10f; }

#define FPS_BODY(i) { \
    const float zj = zs[(i)*FPS_T + t]; \
    const float dx = __fsub_rn(px##i, lx); \
    const float dy = __fsub_rn(py##i, ly); \
    const float dz = __fsub_rn(zj,  lz); \
    const float dist = __fadd_rn(__fadd_rn(__fmul_rn(dx,dx), __fmul_rn(dy,dy)), \
                                 __fmul_rn(dz,dz)); \
    const float dj = fminf(d##i, dist); \
    d##i = dj; \
    if (dj > bestv) { bestv = dj; besti = (i)*FPS_T + t; } }

__launch_bounds__(FPS_T)
__global__ void k_fps(const float* __restrict__ P, float* __restrict__ outp)
{
    __shared__ float zs[FPS_J * FPS_T];   // 33792 floats, 135168 B
    __shared__ float redv[16];
    __shared__ int   redi[16];
    __shared__ int   lastidx_s;

    const int b = blockIdx.x;
    const int t = threadIdx.x;
    const float* __restrict__ Pb = P + b * 99072;
    const float NEG = -__builtin_inff();

    REP32(FPS_DECL)
    float px32, py32, d32;

    REP32(FPS_INIT)
    {   // j = 32: only t < 256 is a real point (32*1024 + 256 = 33024)
        const int p = 32*FPS_T + t;
        if (t < (NFULL - 32*FPS_T)) {
            px32 = Pb[p*3+0]; py32 = Pb[p*3+1]; zs[p] = Pb[p*3+2]; d32 = 1.0e10f;
        } else {
            px32 = 0.f; py32 = 0.f; zs[p] = 0.f; d32 = NEG;   // in-array pad
        }
    }
    __syncthreads();

    int last = 0;
    float* __restrict__ po = outp + b * (512*3);
    for (int s = 0; s < 512; ++s) {
        const float lx = Pb[last*3+0];
        const float ly = Pb[last*3+1];
        const float lz = Pb[last*3+2];
        if (t == 0) { po[s*3+0] = lx; po[s*3+1] = ly; po[s*3+2] = lz; }
        if (s == 511) break;

        float bestv = NEG;
        int   besti = 0x7FFFFFFF;
        // np order: dist = (dx*dx + dy*dy) + dz*dz, no fma contraction;
        // first-max wins (ascending j = ascending global index, strict >)
        REP32(FPS_BODY)
        FPS_BODY(32)

        // wave (64-lane) argmax reduce, min-index tie-break
        #pragma unroll
        for (int m = 1; m < 64; m <<= 1) {
            const float ov = __shfl_xor(bestv, m, 64);
            const int   oi = __shfl_xor(besti, m, 64);
            if (ov > bestv || (ov == bestv && oi < besti)) { bestv = ov; besti = oi; }
        }
        if ((t & 63) == 0) { redv[t >> 6] = bestv; redi[t >> 6] = besti; }
        __syncthreads();
        if (t < 64) {
            float v = (t < 16) ? redv[t] : NEG;
            int   i = (t < 16) ? redi[t] : 0x7FFFFFFF;
            #pragma unroll
            for (int m = 1; m < 16; m <<= 1) {
                const float ov = __shfl_xor(v, m, 64);
                const int   oi = __shfl_xor(i, m, 64);
                if (ov > v || (ov == v && oi < i)) { v = ov; i = oi; }
            }
            if (t == 0) lastidx_s = i;
        }
        __syncthreads();
        last = lastidx_s;
    }
}

extern "C" void kernel_launch(void* const* d_in, const int* in_sizes, int n_in,
                              void* d_out, int out_size, void* d_ws, size_t ws_size,
                              hipStream_t stream)
{
    const float* feat    = (const float*)d_in[0];
    const float* partial = (const float*)d_in[1];
    const float* ps_w    = (const float*)d_in[2];
    const float* ps_b    = (const float*)d_in[3];
    const float* m1_w1   = (const float*)d_in[4];
    const float* m1_b1   = (const float*)d_in[5];
    const float* m1_w2   = (const float*)d_in[6];
    const float* m1_b2   = (const float*)d_in[7];
    const float* m1_ws   = (const float*)d_in[8];
    const float* m1_bs   = (const float*)d_in[9];
    const float* m2_w1   = (const float*)d_in[10];
    const float* m2_b1   = (const float*)d_in[11];
    const float* m2_w2   = (const float*)d_in[12];
    const float* m2_b2   = (const float*)d_in[13];
    const float* m2_ws   = (const float*)d_in[14];
    const float* m2_bs   = (const float*)d_in[15];
    const float* m3_w1   = (const float*)d_in[16];
    const float* m3_b1   = (const float*)d_in[17];
    const float* m3_w2   = (const float*)d_in[18];
    const float* m3_b2   = (const float*)d_in[19];
    const float* m3_ws   = (const float*)d_in[20];
    const float* m3_bs   = (const float*)d_in[21];
    const float* m4_w1   = (const float*)d_in[22];
    const float* m4_b1   = (const float*)d_in[23];
    const float* m4_w2   = (const float*)d_in[24];
    const float* m4_b2   = (const float*)d_in[25];

    float* ws = (float*)d_ws;
    float* P  = ws;               // 32*33024*3 = 3,170,304 floats
    float* A  = ws + 3170304;     // 1,048,576
    float* B  = ws + 4218880;     // 1,048,576
    float* C  = ws + 5267456;     // 1,048,576
    float* FB = ws + 6316032;     // 4*4096 (m1_w1, m1_ws, m3_w1, m3_ws folds)

    float* out = (float*)d_out;   // [0,24576) pcd ; [24576,73728) p0

    k_ps  <<<128,  256, 0, stream>>>(feat, ps_w, ps_b, A);
    k_fb  <<<64,   256, 0, stream>>>(feat, m1_w1, m1_ws, m3_w1, m3_ws, FB);
    k_copy<<<2048, 256, 0, stream>>>(partial, P);

    // m1 (fr folded into FB)
    k_conv<<<32*128, 256, 0, stream>>>(A, m1_w1, m1_b1, FB,       nullptr, B, 128, 128, 640, 1);
    k_conv<<<32*128, 256, 0, stream>>>(A, m1_ws, m1_bs, FB+4096,  nullptr, C, 128, 128, 640, 0);
    k_conv<<<32*128, 256, 0, stream>>>(B, m1_w2, m1_b2, nullptr,  C,       A, 128, 128, 128, 0);
    // m2
    k_conv<<<32*64,  256, 0, stream>>>(A, m2_w1, m2_b1, nullptr,  nullptr, B, 64,  128, 128, 1);
    k_conv<<<32*128, 256, 0, stream>>>(A, m2_ws, m2_bs, nullptr,  nullptr, C, 128, 128, 128, 0);
    k_conv<<<32*128, 256, 0, stream>>>(B, m2_w2, m2_b2, nullptr,  C,       A, 128, 64,  64,  0);
    // m3 (fr folded)
    k_conv<<<32*128, 256, 0, stream>>>(A, m3_w1, m3_b1, FB+8192,  nullptr, B, 128, 128, 640, 1);
    k_conv<<<32*128, 256, 0, stream>>>(A, m3_ws, m3_bs, FB+12288, nullptr, C, 128, 128, 640, 0);
    k_conv<<<32*128, 256, 0, stream>>>(B, m3_w2, m3_b2, nullptr,  C,       A, 128, 128, 128, 0);
    // m4
    k_conv<<<32*64,  256, 0, stream>>>(A, m4_w1, m4_b1, nullptr,  nullptr, B, 64,  128, 128, 1);
    k_conv<<<32*3,   256, 0, stream>>>(B, m4_w2, m4_b2, nullptr,  nullptr, C, 3,   64,  64,  0);

    k_pcd <<<32, 256, 0, stream>>>(C, out, P);
    k_fps <<<32, FPS_T, 0, stream>>>(P, out + 24576);
}

// Round 6
// 3390.906 us; speedup vs baseline: 1.5402x; 1.5402x over previous
//
#include <hip/hip_runtime.h>

#define NFULL 33024
#define FPS_T 512
#define BST   99072    // per-batch stride in XYZ SoA: 3*33024

// ---- x1[b,o,k] = sum_i f[b,i] * ps_w[i,o,k] + ps_b[o] ; col = o*256+k ----
__global__ void k_ps(const float* __restrict__ feat,
                     const float* __restrict__ psw,
                     const float* __restrict__ psb,
                     float* __restrict__ out)
{
    __shared__ float fs[16384];   // all of f (32x512), 64 KB
    const int tid = threadIdx.x;
    for (int k = tid; k < 16384; k += 256) fs[k] = feat[k];
    __syncthreads();
    const int col = blockIdx.x * 256 + tid;    // 0..32767
    float acc[32];
    #pragma unroll
    for (int b = 0; b < 32; ++b) acc[b] = 0.f;
    for (int i = 0; i < 512; i += 4) {
        const float w0 = psw[(i+0)*32768 + col];
        const float w1 = psw[(i+1)*32768 + col];
        const float w2 = psw[(i+2)*32768 + col];
        const float w3 = psw[(i+3)*32768 + col];
        #pragma unroll
        for (int b = 0; b < 32; ++b) {
            const float4 f4 = *(const float4*)&fs[b*512 + i];
            acc[b] += f4.x*w0 + f4.y*w1 + f4.z*w2 + f4.w*w3;
        }
    }
    const float bias = psb[col >> 8];
    #pragma unroll
    for (int b = 0; b < 32; ++b) out[b*32768 + col] = acc[b] + bias;
}

// ---- fb[wsel][b,o] = sum_{i<512} f[b,i] * w[o*640 + 128 + i]  (fr-fold) ----
__global__ void k_fb(const float* __restrict__ feat,
                     const float* __restrict__ wa, const float* __restrict__ wb,
                     const float* __restrict__ wc, const float* __restrict__ wd,
                     float* __restrict__ fb)
{
    const int tid = blockIdx.x * 256 + threadIdx.x;  // 0..16383
    const int wsel = tid >> 12;
    const int r = tid & 4095;
    const int b = r >> 7, o = r & 127;
    const float* w = (wsel == 0 ? wa : wsel == 1 ? wb : wsel == 2 ? wc : wd) + o*640 + 128;
    const float* f = feat + b*512;
    float acc = 0.f;
    for (int i = 0; i < 512; i += 4) {
        const float4 wv = *(const float4*)(w + i);
        const float4 fv = *(const float4*)(f + i);
        acc += wv.x*fv.x + wv.y*fv.y + wv.z*fv.z + wv.w*fv.w;
    }
    fb[tid] = acc;
}

// ---- out[b,o,n] = relu?( sum_i w[o,i]*x[b,i,n] + bias[o] + fb[b,o] + add[b,o,n] )
__global__ void k_conv(const float* __restrict__ x,
                       const float* __restrict__ w,
                       const float* __restrict__ bias,
                       const float* __restrict__ fb,
                       const float* __restrict__ add,
                       float* __restrict__ out,
                       const int O, const int K, const int ldw, const int relu)
{
    const int bo = blockIdx.x;
    const int b = bo / O;
    const int o = bo - b * O;
    const int n = threadIdx.x;
    const float* __restrict__ wr = w + o * ldw;
    const float* __restrict__ xb = x + (b * K) * 256 + n;
    float acc = 0.f;
    for (int i = 0; i < K; i += 4) {
        const float4 wv = *(const float4*)(wr + i);
        acc += wv.x * xb[(i+0) << 8];
        acc += wv.y * xb[(i+1) << 8];
        acc += wv.z * xb[(i+2) << 8];
        acc += wv.w * xb[(i+3) << 8];
    }
    acc += bias[o];
    if (fb)   acc += fb[b * O + o];
    if (add)  acc += add[bo * 256 + n];
    if (relu) acc = fmaxf(acc, 0.f);
    out[bo * 256 + n] = acc;
}

// ---- pcd transpose -> d_out ; completion points -> XYZ SoA [0,256) ----
__global__ void k_pcd(const float* __restrict__ comp,
                      float* __restrict__ pcd_out,
                      float* __restrict__ XYZ)
{
    const int tid = blockIdx.x * 256 + threadIdx.x;  // 0..8191
    const int b = tid >> 8, n = tid & 255;
    const float cx = comp[(b*3+0)*256 + n];
    const float cy = comp[(b*3+1)*256 + n];
    const float cz = comp[(b*3+2)*256 + n];
    pcd_out[tid*3+0] = cx; pcd_out[tid*3+1] = cy; pcd_out[tid*3+2] = cz;
    float* Xb = XYZ + b*BST;
    Xb[n]           = cx;
    Xb[33024  + n]  = cy;
    Xb[66048  + n]  = cz;
}

// ---- partial (AoS) -> XYZ SoA [256,33024) per batch (bitwise) ----
__global__ void k_copy(const float* __restrict__ partial, float* __restrict__ XYZ)
{
    const int p = blockIdx.x*256 + threadIdx.x;   // 0..1048575 (32*32768)
    const int b = p >> 15, i = p & 32767;
    const float x = partial[p*3+0];
    const float y = partial[p*3+1];
    const float z = partial[p*3+2];
    float* Xb = XYZ + b*BST;
    Xb[256 + i]          = x;
    Xb[33024 + 256 + i]  = y;
    Xb[66048 + 256 + i]  = z;
}

// ================= farthest point sampling =================
// One 512-thread block per batch. The allocator gives this shape 128 VGPRs
// no matter what (observed r1-r5); so ONLY the mutable d-state lives in
// registers (68 named scalars + ~30 temps < 128). Read-only coords: z in
// LDS (129KB), x/y re-streamed per step as coalesced float4 from L2-resident
// SoA. Mapping p = jo*2048 + 4t + c is lane-coalesced AND per-thread
// ascending (jo major, c minor) so strict-> scan = np first-max semantics.

#define REP16(M) \
  M(0) M(1) M(2) M(3) M(4) M(5) M(6) M(7) \
  M(8) M(9) M(10) M(11) M(12) M(13) M(14) M(15)

#define FPS_DECL(jo) float d##jo##_0 = 1.0e10f, d##jo##_1 = 1.0e10f, \
                           d##jo##_2 = 1.0e10f, d##jo##_3 = 1.0e10f;

#define FBODY(xx, yy, zz, dd, pp) { \
    const float dx = __fsub_rn((xx), lx); \
    const float dy = __fsub_rn((yy), ly); \
    const float dz = __fsub_rn((zz), lz); \
    const float dist = __fadd_rn(__fadd_rn(__fmul_rn(dx,dx), __fmul_rn(dy,dy)), \
                                 __fmul_rn(dz,dz)); \
    dd = fminf(dd, dist); \
    if (dd > bestv) { bestv = dd; besti = (pp); } }

#define FPS_GRP(jo) { \
    const float4 x4 = *(const float4*)(Xb + (jo)*2048 + t4); \
    const float4 y4 = *(const float4*)(Yb + (jo)*2048 + t4); \
    const float4 z4 = *(const float4*)(zs + (jo)*2048 + t4); \
    FBODY(x4.x, y4.x, z4.x, d##jo##_0, (jo)*2048 + t4 + 0) \
    FBODY(x4.y, y4.y, z4.y, d##jo##_1, (jo)*2048 + t4 + 1) \
    FBODY(x4.z, y4.z, z4.z, d##jo##_2, (jo)*2048 + t4 + 2) \
    FBODY(x4.w, y4.w, z4.w, d##jo##_3, (jo)*2048 + t4 + 3) }

__launch_bounds__(FPS_T)
__global__ void k_fps(const float* __restrict__ XYZ, float* __restrict__ outp)
{
    __shared__ __align__(16) float zs[NFULL];   // 132,096 B
    __shared__ float redv[8];
    __shared__ int   redi[8];
    __shared__ int   lastidx_s;

    const int b = blockIdx.x;
    const int t = threadIdx.x;
    const int t4 = t << 2;
    const float* __restrict__ Xb = XYZ + b*BST;
    const float* __restrict__ Yb = Xb + 33024;
    const float* __restrict__ Zb = Xb + 66048;
    const float NEG = -__builtin_inff();

    for (int k = t; k < NFULL; k += FPS_T) zs[k] = Zb[k];

    REP16(FPS_DECL)
    float dt_0 = 1.0e10f, dt_1 = 1.0e10f, dt_2 = 1.0e10f, dt_3 = 1.0e10f;
    __syncthreads();

    int last = 0;
    float* __restrict__ po = outp + b * (512*3);
    for (int s = 0; s < 512; ++s) {
        const float lx = Xb[last];
        const float ly = Yb[last];
        const float lz = zs[last];            // bitwise == Zb[last]
        if (t == 0) { po[s*3+0] = lx; po[s*3+1] = ly; po[s*3+2] = lz; }
        if (s == 511) break;

        float bestv = NEG;
        int   besti = 0x7FFFFFFF;
        // np order: dist = (dx*dx + dy*dy) + dz*dz, no fma; strict-> scan
        REP16(FPS_GRP)
        if (t < 64) {   // tail points 32768..33023 (64 threads x 4)
            const float4 x4 = *(const float4*)(Xb + 32768 + t4);
            const float4 y4 = *(const float4*)(Yb + 32768 + t4);
            const float4 z4 = *(const float4*)(zs + 32768 + t4);
            FBODY(x4.x, y4.x, z4.x, dt_0, 32768 + t4 + 0)
            FBODY(x4.y, y4.y, z4.y, dt_1, 32768 + t4 + 1)
            FBODY(x4.z, y4.z, z4.z, dt_2, 32768 + t4 + 2)
            FBODY(x4.w, y4.w, z4.w, dt_3, 32768 + t4 + 3)
        }

        // wave (64-lane) argmax reduce, min-index tie-break
        #pragma unroll
        for (int m = 1; m < 64; m <<= 1) {
            const float ov = __shfl_xor(bestv, m, 64);
            const int   oi = __shfl_xor(besti, m, 64);
            if (ov > bestv || (ov == bestv && oi < besti)) { bestv = ov; besti = oi; }
        }
        if ((t & 63) == 0) { redv[t >> 6] = bestv; redi[t >> 6] = besti; }
        __syncthreads();
        if (t < 64) {
            float v = (t < 8) ? redv[t] : NEG;
            int   i = (t < 8) ? redi[t] : 0x7FFFFFFF;
            #pragma unroll
            for (int m = 1; m < 8; m <<= 1) {
                const float ov = __shfl_xor(v, m, 64);
                const int   oi = __shfl_xor(i, m, 64);
                if (ov > v || (ov == v && oi < i)) { v = ov; i = oi; }
            }
            if (t == 0) lastidx_s = i;
        }
        __syncthreads();
        last = lastidx_s;
    }
}

extern "C" void kernel_launch(void* const* d_in, const int* in_sizes, int n_in,
                              void* d_out, int out_size, void* d_ws, size_t ws_size,
                              hipStream_t stream)
{
    const float* feat    = (const float*)d_in[0];
    const float* partial = (const float*)d_in[1];
    const float* ps_w    = (const float*)d_in[2];
    const float* ps_b    = (const float*)d_in[3];
    const float* m1_w1   = (const float*)d_in[4];
    const float* m1_b1   = (const float*)d_in[5];
    const float* m1_w2   = (const float*)d_in[6];
    const float* m1_b2   = (const float*)d_in[7];
    const float* m1_ws   = (const float*)d_in[8];
    const float* m1_bs   = (const float*)d_in[9];
    const float* m2_w1   = (const float*)d_in[10];
    const float* m2_b1   = (const float*)d_in[11];
    const float* m2_w2   = (const float*)d_in[12];
    const float* m2_b2   = (const float*)d_in[13];
    const float* m2_ws   = (const float*)d_in[14];
    const float* m2_bs   = (const float*)d_in[15];
    const float* m3_w1   = (const float*)d_in[16];
    const float* m3_b1   = (const float*)d_in[17];
    const float* m3_w2   = (const float*)d_in[18];
    const float* m3_b2   = (const float*)d_in[19];
    const float* m3_ws   = (const float*)d_in[20];
    const float* m3_bs   = (const float*)d_in[21];
    const float* m4_w1   = (const float*)d_in[22];
    const float* m4_b1   = (const float*)d_in[23];
    const float* m4_w2   = (const float*)d_in[24];
    const float* m4_b2   = (const float*)d_in[25];

    float* ws = (float*)d_ws;
    float* XYZ = ws;              // 32*3*33024 = 3,170,304 floats (SoA per batch)
    float* A  = ws + 3170304;     // 1,048,576
    float* B  = ws + 4218880;     // 1,048,576
    float* C  = ws + 5267456;     // 1,048,576
    float* FB = ws + 6316032;     // 4*4096 (m1_w1, m1_ws, m3_w1, m3_ws folds)

    float* out = (float*)d_out;   // [0,24576) pcd ; [24576,73728) p0

    k_ps  <<<128,  256, 0, stream>>>(feat, ps_w, ps_b, A);
    k_fb  <<<64,   256, 0, stream>>>(feat, m1_w1, m1_ws, m3_w1, m3_ws, FB);
    k_copy<<<4096, 256, 0, stream>>>(partial, XYZ);

    // m1 (fr folded into FB)
    k_conv<<<32*128, 256, 0, stream>>>(A, m1_w1, m1_b1, FB,       nullptr, B, 128, 128, 640, 1);
    k_conv<<<32*128, 256, 0, stream>>>(A, m1_ws, m1_bs, FB+4096,  nullptr, C, 128, 128, 640, 0);
    k_conv<<<32*128, 256, 0, stream>>>(B, m1_w2, m1_b2, nullptr,  C,       A, 128, 128, 128, 0);
    // m2
    k_conv<<<32*64,  256, 0, stream>>>(A, m2_w1, m2_b1, nullptr,  nullptr, B, 64,  128, 128, 1);
    k_conv<<<32*128, 256, 0, stream>>>(A, m2_ws, m2_bs, nullptr,  nullptr, C, 128, 128, 128, 0);
    k_conv<<<32*128, 256, 0, stream>>>(B, m2_w2, m2_b2, nullptr,  C,       A, 128, 64,  64,  0);
    // m3 (fr folded)
    k_conv<<<32*128, 256, 0, stream>>>(A, m3_w1, m3_b1, FB+8192,  nullptr, B, 128, 128, 640, 1);
    k_conv<<<32*128, 256, 0, stream>>>(A, m3_ws, m3_bs, FB+12288, nullptr, C, 128, 128, 640, 0);
    k_conv<<<32*128, 256, 0, stream>>>(B, m3_w2, m3_b2, nullptr,  C,       A, 128, 128, 128, 0);
    // m4
    k_conv<<<32*64,  256, 0, stream>>>(A, m4_w1, m4_b1, nullptr,  nullptr, B, 64,  128, 128, 1);
    k_conv<<<32*3,   256, 0, stream>>>(B, m4_w2, m4_b2, nullptr,  nullptr, C, 3,   64,  64,  0);

    k_pcd <<<32, 256, 0, stream>>>(C, out, XYZ);
    k_fps <<<32, FPS_T, 0, stream>>>(XYZ, out + 24576);
}